// Round 6
// baseline (544.761 us; speedup 1.0000x reference)
//
#include <hip/hip_runtime.h>
#include <math.h>

#define NODES 30000
#define EDGES 600000
#define OUT_W 256
#define BN_EPS 1e-5f

typedef __attribute__((ext_vector_type(8))) __bf16 bf16x8;
typedef __attribute__((ext_vector_type(4))) float f32x4;

__device__ __forceinline__ unsigned short f2bf(float f) {
    union { float f; unsigned int u; } v; v.f = f;
    unsigned int r = v.u + 0x7FFFu + ((v.u >> 16) & 1u);   // RNE
    return (unsigned short)(r >> 16);
}
__device__ __forceinline__ float bf2f(unsigned short u) {
    union { unsigned int u; float f; } v; v.u = ((unsigned int)u) << 16;
    return v.f;
}

typedef const __attribute__((address_space(1))) void* gas_p;
typedef __attribute__((address_space(3))) void* las_p;
__device__ __forceinline__ void gload_lds16(const void* g, void* l) {
    __builtin_amdgcn_global_load_lds((gas_p)g, (las_p)l, 16, 0, 0);
}

// ---------------- CSR build ----------------

__global__ __launch_bounds__(256) void k_count(const int* __restrict__ ei, int* __restrict__ deg) {
    int e = blockIdx.x * 256 + threadIdx.x;
    if (e < EDGES) atomicAdd(&deg[ei[EDGES + e]], 1);   // dst row
}

__global__ __launch_bounds__(256) void k_blocksum(const int* __restrict__ deg, int* __restrict__ bsum) {
    __shared__ int sh[256];
    int i = blockIdx.x * 256 + threadIdx.x;
    sh[threadIdx.x] = (i < NODES) ? deg[i] : 0;
    __syncthreads();
    for (int off = 128; off > 0; off >>= 1) {
        if (threadIdx.x < off) sh[threadIdx.x] += sh[threadIdx.x + off];
        __syncthreads();
    }
    if (threadIdx.x == 0) bsum[blockIdx.x] = sh[0];
}

__global__ void k_scanb(const int* __restrict__ bsum, int* __restrict__ bbase, int nb) {
    if (threadIdx.x == 0 && blockIdx.x == 0) {
        int run = 0;
        for (int b = 0; b < nb; b++) { bbase[b] = run; run += bsum[b]; }
    }
}

__global__ __launch_bounds__(256) void k_localscan(const int* __restrict__ deg, const int* __restrict__ bbase,
                                                   int* __restrict__ rowptr, int* __restrict__ cursor) {
    __shared__ int sh[256];
    int i = blockIdx.x * 256 + threadIdx.x;
    int v = (i < NODES) ? deg[i] : 0;
    sh[threadIdx.x] = v;
    __syncthreads();
    for (int off = 1; off < 256; off <<= 1) {
        int add = (threadIdx.x >= off) ? sh[threadIdx.x - off] : 0;
        __syncthreads();
        sh[threadIdx.x] += add;
        __syncthreads();
    }
    if (i < NODES) {
        int p = bbase[blockIdx.x] + sh[threadIdx.x] - v;  // exclusive
        rowptr[i] = p;
        cursor[i] = p;
    }
}

__global__ __launch_bounds__(256) void k_fill(const int* __restrict__ ei, int* __restrict__ cursor,
                                              int* __restrict__ csr_src) {
    int e = blockIdx.x * 256 + threadIdx.x;
    if (e < EDGES) {
        int s = ei[e];
        int d = ei[EDGES + e];
        int slot = atomicAdd(&cursor[d], 1);
        csr_src[slot] = s;
    }
}

// ---------------- casts ----------------

__global__ __launch_bounds__(256) void k_castA(const float* __restrict__ in, unsigned short* __restrict__ out, int n8) {
    int i = blockIdx.x * 256 + threadIdx.x;
    if (i >= n8) return;
    const float4* p = (const float4*)(in + (size_t)i * 8);
    float4 v0 = p[0], v1 = p[1];
    ushort4 o0, o1;
    o0.x = f2bf(v0.x); o0.y = f2bf(v0.y); o0.z = f2bf(v0.z); o0.w = f2bf(v0.w);
    o1.x = f2bf(v1.x); o1.y = f2bf(v1.y); o1.z = f2bf(v1.z); o1.w = f2bf(v1.w);
    ushort4* q = (ushort4*)(out + (size_t)i * 8);
    q[0] = o0; q[1] = o1;
}

// W (256x256 fp32, 4 of them) -> fused Wt [1024 x 256] bf16, row n = output column; + fused bias
__global__ __launch_bounds__(256) void k_castW(
    const float* __restrict__ W0, const float* __restrict__ W1,
    const float* __restrict__ W2, const float* __restrict__ W3,
    const float* __restrict__ B0, const float* __restrict__ B1,
    const float* __restrict__ B2, const float* __restrict__ B3,
    unsigned short* __restrict__ Wt, float* __restrict__ bfused)
{
    int n = blockIdx.x;           // 0..1023
    int k = threadIdx.x;          // 0..255
    int wsel = n >> 8, nn = n & 255;
    const float* W  = (wsel == 0) ? W0 : (wsel == 1) ? W1 : (wsel == 2) ? W2 : W3;
    const float* Bv = (wsel == 0) ? B0 : (wsel == 1) ? B1 : (wsel == 2) ? B2 : B3;
    Wt[(size_t)n * 256 + k] = f2bf(W[(size_t)k * 256 + nn]);
    if (k == 0) bfused[n] = Bv[nn];
}

// ---------------- bf16 MFMA GEMM, BK=64, split epilogue ----------------
// output col c: 0..255 = q -> qs[node][c] bf16 ; 256..511 = k -> k8[node][c-256] fp8
// 512..767 = v -> vb[node][c-512] bf16 ; 768..1023 = s -> qs[node][256 + c-768] bf16

__global__ __launch_bounds__(256) void k_gemm_bf16(
    const unsigned short* __restrict__ A,
    const unsigned short* __restrict__ Wt,
    const float* __restrict__ bias,
    unsigned short* __restrict__ qs,
    unsigned char* __restrict__ k8,
    unsigned short* __restrict__ vb, int M)
{
    __shared__ unsigned short As[128 * 64];
    __shared__ unsigned short Bs[128 * 64];
    int tid = threadIdx.x;
    int lane = tid & 63;
    int wave = tid >> 6;
    int wm = wave & 1, wn = wave >> 1;      // 2x2 waves -> 64x64 each
    int row0 = blockIdx.x * 128;
    int n0 = blockIdx.y * 128;
    int y = blockIdx.y;

    f32x4 acc[4][4] = {};

    for (int k0 = 0; k0 < 256; k0 += 64) {
        // stage 128x64 tiles: chunk c = w*256+tid; row=c>>3, col8=(c&7)*8; dest elem = c*8
        #pragma unroll
        for (int w = 0; w < 4; w++) {
            int c = w * 256 + tid;
            int row = c >> 3;
            int cole = (c & 7) * 8;
            int ar = row0 + row; if (ar >= M) ar = M - 1;
            gload_lds16(&A[(size_t)ar * 256 + k0 + cole], &As[w * 2048 + tid * 8]);
            gload_lds16(&Wt[(size_t)(n0 + row) * 256 + k0 + cole], &Bs[w * 2048 + tid * 8]);
        }
        __syncthreads();
        int rsel = lane & 15;
        int kq = (lane >> 4) * 8;
        #pragma unroll
        for (int kh = 0; kh < 2; kh++) {
            bf16x8 af[4], bf[4];
            #pragma unroll
            for (int t = 0; t < 4; t++) {
                af[t] = *reinterpret_cast<const bf16x8*>(&As[(wm * 64 + t * 16 + rsel) * 64 + kh * 32 + kq]);
                bf[t] = *reinterpret_cast<const bf16x8*>(&Bs[(wn * 64 + t * 16 + rsel) * 64 + kh * 32 + kq]);
            }
            #pragma unroll
            for (int mt = 0; mt < 4; mt++)
                #pragma unroll
                for (int nt = 0; nt < 4; nt++)
                    acc[mt][nt] = __builtin_amdgcn_mfma_f32_16x16x32_bf16(af[mt], bf[nt], acc[mt][nt], 0, 0, 0);
        }
        __syncthreads();
    }

    // C/D mapping (verified m89/m91): col = lane&15, row = (lane>>4)*4 + reg
    int crow = (lane >> 4) * 4;
    int ccol = lane & 15;
    #pragma unroll
    for (int mt = 0; mt < 4; mt++) {
        int grow = row0 + wm * 64 + mt * 16 + crow;
        #pragma unroll
        for (int nt = 0; nt < 4; nt++) {
            int gcol = n0 + wn * 64 + nt * 16 + ccol;
            float bv = bias[gcol];
            #pragma unroll
            for (int r = 0; r < 4; r++) {
                int rr = grow + r;
                if (rr >= M) continue;
                float val = acc[mt][nt][r] + bv;
                if (y < 2) {
                    qs[(size_t)rr * 512 + gcol] = f2bf(val);
                } else if (y < 4) {
                    int p8 = __builtin_amdgcn_cvt_pk_fp8_f32(val, val, 0, false);
                    k8[(size_t)rr * 256 + (gcol - 256)] = (unsigned char)p8;
                } else if (y < 6) {
                    vb[(size_t)rr * 256 + (gcol - 512)] = f2bf(val);
                } else {
                    qs[(size_t)rr * 512 + (gcol - 512)] = f2bf(val);
                }
            }
        }
    }
}

// ---------------- attention (fp8 k, bf16 q/v/s): one wave per node, depth-2 prefetch ----------------
// lane l owns channels 4l..4l+3; head = l>>4; per-head reduce = xor shuffle within 16-lane group.

__global__ __launch_bounds__(256) void k_attn(const unsigned short* __restrict__ qs,
                                              const unsigned char* __restrict__ k8,
                                              const unsigned short* __restrict__ vb,
                                              const int* __restrict__ rowptr,
                                              const int* __restrict__ deg,
                                              const int* __restrict__ csr_src,
                                              float* __restrict__ out)
{
    int wave = threadIdx.x >> 6;
    int lane = threadIdx.x & 63;
    int node = blockIdx.x * 4 + wave;
    if (node >= NODES) return;

    const unsigned short* qrow = qs + (size_t)node * 512;
    float q0, q1, q2, q3;
    {
        ushort4 qv = *(const ushort4*)&qrow[lane * 4];
        q0 = bf2f(qv.x); q1 = bf2f(qv.y); q2 = bf2f(qv.z); q3 = bf2f(qv.w);
    }

    float m = -INFINITY, L = 0.f;
    float a0 = 0.f, a1 = 0.f, a2 = 0.f, a3 = 0.f;

    int start = rowptr[node];
    int cnt = deg[node];

    // depth-2 pipeline: while consuming edge e, loads for e+1 and e+2 are in flight
    int kwA = 0, kwB = 0;
    ushort4 vvA, vvB;
    if (cnt > 0) {
        int s0 = csr_src[start];
        kwA = *(const int*)&k8[(size_t)s0 * 256 + lane * 4];
        vvA = *(const ushort4*)&vb[(size_t)s0 * 256 + lane * 4];
    }
    if (cnt > 1) {
        int s1 = csr_src[start + 1];
        kwB = *(const int*)&k8[(size_t)s1 * 256 + lane * 4];
        vvB = *(const ushort4*)&vb[(size_t)s1 * 256 + lane * 4];
    }
    for (int e = 0; e < cnt; e++) {
        int kwN = 0; ushort4 vvN;
        if (e + 2 < cnt) {
            int sn = csr_src[start + e + 2];
            kwN = *(const int*)&k8[(size_t)sn * 256 + lane * 4];
            vvN = *(const ushort4*)&vb[(size_t)sn * 256 + lane * 4];
        }
        float dot = q0 * __builtin_amdgcn_cvt_f32_fp8(kwA, 0)
                  + q1 * __builtin_amdgcn_cvt_f32_fp8(kwA, 1)
                  + q2 * __builtin_amdgcn_cvt_f32_fp8(kwA, 2)
                  + q3 * __builtin_amdgcn_cvt_f32_fp8(kwA, 3);
        dot += __shfl_xor(dot, 1, 64);
        dot += __shfl_xor(dot, 2, 64);
        dot += __shfl_xor(dot, 4, 64);
        dot += __shfl_xor(dot, 8, 64);       // per-head sum within 16-lane group
        float alpha = dot * 0.125f;          // / sqrt(64)
        float nm = fmaxf(m, alpha);
        float sc = __expf(m - nm);           // exp(-inf)=0 on first edge
        float p  = __expf(alpha - nm);
        L  = L * sc + p;
        a0 = a0 * sc + p * bf2f(vvA.x);
        a1 = a1 * sc + p * bf2f(vvA.y);
        a2 = a2 * sc + p * bf2f(vvA.z);
        a3 = a3 * sc + p * bf2f(vvA.w);
        m = nm;
        kwA = kwB; vvA = vvB;
        kwB = kwN; vvB = vvN;
    }

    float inv = (L > 0.f) ? 1.f / L : 0.f;
    ushort4 sv = *(const ushort4*)&qrow[256 + lane * 4];
    float4 o;
    o.x = a0 * inv + bf2f(sv.x);
    o.y = a1 * inv + bf2f(sv.y);
    o.z = a2 * inv + bf2f(sv.z);
    o.w = a3 * inv + bf2f(sv.w);
    *(float4*)&out[(size_t)node * OUT_W + lane * 4] = o;
}

// ---------------- BatchNorm ----------------

__global__ __launch_bounds__(256) void k_bnstats(const float* __restrict__ h,
                                                 float* __restrict__ sum, float* __restrict__ sumsq) {
    int col = threadIdx.x;
    int r0 = blockIdx.x * 64;
    int r1 = min(r0 + 64, NODES);
    float s = 0.f, s2 = 0.f;
    for (int r = r0; r < r1; r++) {
        float v = h[(size_t)r * OUT_W + col];
        s += v; s2 += v * v;
    }
    atomicAdd(&sum[col], s);
    atomicAdd(&sumsq[col], s2);
}

__device__ __forceinline__ float4 bn_scale4(const float* sum, const float* sumsq,
                                            const float* g, const float* be,
                                            int col, float4* shift) {
    float4 s  = *(const float4*)&sum[col];
    float4 s2 = *(const float4*)&sumsq[col];
    float4 gv = *(const float4*)&g[col];
    float4 bv = *(const float4*)&be[col];
    const float invN = 1.0f / NODES;
    float4 sc, sh;
    float mean, var;
    mean = s.x * invN; var = fmaxf(s2.x * invN - mean * mean, 0.f);
    sc.x = gv.x * rsqrtf(var + BN_EPS); sh.x = bv.x - mean * sc.x;
    mean = s.y * invN; var = fmaxf(s2.y * invN - mean * mean, 0.f);
    sc.y = gv.y * rsqrtf(var + BN_EPS); sh.y = bv.y - mean * sc.y;
    mean = s.z * invN; var = fmaxf(s2.z * invN - mean * mean, 0.f);
    sc.z = gv.z * rsqrtf(var + BN_EPS); sh.z = bv.z - mean * sc.z;
    mean = s.w * invN; var = fmaxf(s2.w * invN - mean * mean, 0.f);
    sc.w = gv.w * rsqrtf(var + BN_EPS); sh.w = bv.w - mean * sc.w;
    *shift = sh;
    return sc;
}

// layer-1 apply: fp32 in -> bf16 out (feeds GEMM2); scale/shift computed inline
__global__ __launch_bounds__(256) void k_bnapply_bf16(const float* __restrict__ h,
                                                      const float* __restrict__ sum,
                                                      const float* __restrict__ sumsq,
                                                      const float* __restrict__ g,
                                                      const float* __restrict__ be,
                                                      unsigned short* __restrict__ out) {
    int idx = blockIdx.x * 256 + threadIdx.x;
    int base = idx * 4;
    int col = base & (OUT_W - 1);
    float4 sh;
    float4 sc = bn_scale4(sum, sumsq, g, be, col, &sh);
    float4 v = *(const float4*)&h[base];
    float4 o;
    o.x = v.x * sc.x + sh.x; o.x = (o.x >= 0.f) ? o.x : 0.1f * o.x;
    o.y = v.y * sc.y + sh.y; o.y = (o.y >= 0.f) ? o.y : 0.1f * o.y;
    o.z = v.z * sc.z + sh.z; o.z = (o.z >= 0.f) ? o.z : 0.1f * o.z;
    o.w = v.w * sc.w + sh.w; o.w = (o.w >= 0.f) ? o.w : 0.1f * o.w;
    ushort4 u; u.x = f2bf(o.x); u.y = f2bf(o.y); u.z = f2bf(o.z); u.w = f2bf(o.w);
    *(ushort4*)&out[base] = u;
}

// layer-2 apply: fp32 in -> fp32 out (final output); scale/shift computed inline
__global__ __launch_bounds__(256) void k_bnapply(const float* __restrict__ h,
                                                 const float* __restrict__ sum,
                                                 const float* __restrict__ sumsq,
                                                 const float* __restrict__ g,
                                                 const float* __restrict__ be,
                                                 float* __restrict__ out) {
    int idx = blockIdx.x * 256 + threadIdx.x;
    int base = idx * 4;
    int col = base & (OUT_W - 1);
    float4 sh;
    float4 sc = bn_scale4(sum, sumsq, g, be, col, &sh);
    float4 v = *(const float4*)&h[base];
    float4 o;
    o.x = v.x * sc.x + sh.x; o.x = (o.x >= 0.f) ? o.x : 0.1f * o.x;
    o.y = v.y * sc.y + sh.y; o.y = (o.y >= 0.f) ? o.y : 0.1f * o.y;
    o.z = v.z * sc.z + sh.z; o.z = (o.z >= 0.f) ? o.z : 0.1f * o.z;
    o.w = v.w * sc.w + sh.w; o.w = (o.w >= 0.f) ? o.w : 0.1f * o.w;
    *(float4*)&out[base] = o;
}

// ---------------- launch ----------------

extern "C" void kernel_launch(void* const* d_in, const int* in_sizes, int n_in,
                              void* d_out, int out_size, void* d_ws, size_t ws_size,
                              hipStream_t stream) {
    const float* x  = (const float*)d_in[0];
    const int*   ei = (const int*)d_in[1];
    const float* w1[4] = {(const float*)d_in[2], (const float*)d_in[4], (const float*)d_in[6], (const float*)d_in[8]};
    const float* b1[4] = {(const float*)d_in[3], (const float*)d_in[5], (const float*)d_in[7], (const float*)d_in[9]};
    const float* g1  = (const float*)d_in[10];
    const float* be1 = (const float*)d_in[11];
    const float* w2[4] = {(const float*)d_in[12], (const float*)d_in[14], (const float*)d_in[16], (const float*)d_in[18]};
    const float* b2[4] = {(const float*)d_in[13], (const float*)d_in[15], (const float*)d_in[17], (const float*)d_in[19]};
    const float* g2  = (const float*)d_in[20];
    const float* be2 = (const float*)d_in[21];

    char* ws = (char*)d_ws;
    unsigned short* qs     = (unsigned short*)(ws);                 // 30,720,000 (bf16 q|s)
    unsigned char*  k8     = (unsigned char*)(ws + 30720000);       // 7,680,000 (fp8 k)
    unsigned short* vb     = (unsigned short*)(ws + 38400000);      // 15,360,000 (bf16 v)
    float*          h1     = (float*)(ws + 53760000);               // 30,720,000
    unsigned short* abuf   = (unsigned short*)(ws + 84480000);      // 15,360,000 (bf16 GEMM input)
    unsigned short* wt1    = (unsigned short*)(ws + 99840000);      // 524,288
    unsigned short* wt2    = (unsigned short*)(ws + 100364288);     // 524,288
    float*          b1f    = (float*)(ws + 100888576);              // 4,096
    float*          b2f    = (float*)(ws + 100892672);              // 4,096
    int*            deg    = (int*)  (ws + 100896768);              // 120,000
    int*            rowptr = (int*)  (ws + 101016768);              // 120,000
    int*            cursor = (int*)  (ws + 101136768);              // 120,000
    int*            csr    = (int*)  (ws + 101256768);              // 2,400,000
    int*            bsum   = (int*)  (ws + 103656768);              // 512
    int*            bbase  = (int*)  (ws + 103657280);              // 512
    float*          sum1   = (float*)(ws + 103657792);              // 4 x 1024 contiguous
    float*          sq1    = (float*)(ws + 103658816);
    float*          sum2   = (float*)(ws + 103659840);
    float*          sq2    = (float*)(ws + 103660864);

    hipMemsetAsync(deg, 0, NODES * sizeof(int), stream);
    hipMemsetAsync(sum1, 0, 4096, stream);   // sum1/sq1/sum2/sq2 contiguous

    const int EB = (EDGES + 255) / 256;       // 2344
    const int NB = (NODES + 255) / 256;       // 118

    // casts
    k_castA<<<(NODES * 256 / 8 + 255) / 256, 256, 0, stream>>>(x, abuf, NODES * 256 / 8);
    k_castW<<<1024, 256, 0, stream>>>(w1[0], w1[1], w1[2], w1[3], b1[0], b1[1], b1[2], b1[3], wt1, b1f);
    k_castW<<<1024, 256, 0, stream>>>(w2[0], w2[1], w2[2], w2[3], b2[0], b2[1], b2[2], b2[3], wt2, b2f);

    // CSR (shared by both layers)
    k_count    <<<EB, 256, 0, stream>>>(ei, deg);
    k_blocksum <<<NB, 256, 0, stream>>>(deg, bsum);
    k_scanb    <<<1, 64, 0, stream>>>(bsum, bbase, NB);
    k_localscan<<<NB, 256, 0, stream>>>(deg, bbase, rowptr, cursor);
    k_fill     <<<EB, 256, 0, stream>>>(ei, cursor, csr);

    dim3 ggrid((NODES + 127) / 128, 8);       // 235 x 8
    const int ANB = NODES / 4;                // 7500
    const int APB = (NODES * OUT_W / 4) / 256;// 7500
    const int SNB = (NODES + 63) / 64;        // 469

    // layer 1
    k_gemm_bf16  <<<ggrid, 256, 0, stream>>>(abuf, wt1, b1f, qs, k8, vb, NODES);
    k_attn       <<<ANB, 256, 0, stream>>>(qs, k8, vb, rowptr, deg, csr, h1);
    k_bnstats    <<<SNB, 256, 0, stream>>>(h1, sum1, sq1);
    k_bnapply_bf16<<<APB, 256, 0, stream>>>(h1, sum1, sq1, g1, be1, abuf);

    // layer 2
    k_gemm_bf16  <<<ggrid, 256, 0, stream>>>(abuf, wt2, b2f, qs, k8, vb, NODES);
    k_attn       <<<ANB, 256, 0, stream>>>(qs, k8, vb, rowptr, deg, csr, h1);
    k_bnstats    <<<SNB, 256, 0, stream>>>(h1, sum2, sq2);
    k_bnapply    <<<APB, 256, 0, stream>>>(h1, sum2, sq2, g2, be2, (float*)d_out);
}

// Round 7
// 533.755 us; speedup vs baseline: 1.0206x; 1.0206x over previous
//
#include <hip/hip_runtime.h>
#include <math.h>

#define NODES 30000
#define EDGES 600000
#define QKVS_W 1024
#define OUT_W 256
#define BN_EPS 1e-5f

typedef __attribute__((ext_vector_type(8))) __bf16 bf16x8;
typedef __attribute__((ext_vector_type(4))) float f32x4;

__device__ __forceinline__ unsigned short f2bf(float f) {
    union { float f; unsigned int u; } v; v.f = f;
    unsigned int r = v.u + 0x7FFFu + ((v.u >> 16) & 1u);   // RNE
    return (unsigned short)(r >> 16);
}
__device__ __forceinline__ float bf2f(unsigned short u) {
    union { unsigned int u; float f; } v; v.u = ((unsigned int)u) << 16;
    return v.f;
}

typedef const __attribute__((address_space(1))) void* gas_p;
typedef __attribute__((address_space(3))) void* las_p;
__device__ __forceinline__ void gload_lds16(const void* g, void* l) {
    __builtin_amdgcn_global_load_lds((gas_p)g, (las_p)l, 16, 0, 0);
}

// ---------------- CSR build ----------------

__global__ __launch_bounds__(256) void k_count(const int* __restrict__ ei, int* __restrict__ deg) {
    int e = blockIdx.x * 256 + threadIdx.x;
    if (e < EDGES) atomicAdd(&deg[ei[EDGES + e]], 1);   // dst row
}

__global__ __launch_bounds__(256) void k_blocksum(const int* __restrict__ deg, int* __restrict__ bsum) {
    __shared__ int sh[256];
    int i = blockIdx.x * 256 + threadIdx.x;
    sh[threadIdx.x] = (i < NODES) ? deg[i] : 0;
    __syncthreads();
    for (int off = 128; off > 0; off >>= 1) {
        if (threadIdx.x < off) sh[threadIdx.x] += sh[threadIdx.x + off];
        __syncthreads();
    }
    if (threadIdx.x == 0) bsum[blockIdx.x] = sh[0];
}

// parallel exclusive scan over <=128 block sums (LDS Hillis-Steele)
__global__ __launch_bounds__(128) void k_scanb(const int* __restrict__ bsum, int* __restrict__ bbase, int nb) {
    __shared__ int sh[128];
    int t = threadIdx.x;
    int v = (t < nb) ? bsum[t] : 0;
    sh[t] = v;
    __syncthreads();
    for (int off = 1; off < 128; off <<= 1) {
        int add = (t >= off) ? sh[t - off] : 0;
        __syncthreads();
        sh[t] += add;
        __syncthreads();
    }
    if (t < nb) bbase[t] = sh[t] - v;   // exclusive
}

__global__ __launch_bounds__(256) void k_localscan(const int* __restrict__ deg, const int* __restrict__ bbase,
                                                   int* __restrict__ rowptr, int* __restrict__ cursor) {
    __shared__ int sh[256];
    int i = blockIdx.x * 256 + threadIdx.x;
    int v = (i < NODES) ? deg[i] : 0;
    sh[threadIdx.x] = v;
    __syncthreads();
    for (int off = 1; off < 256; off <<= 1) {
        int add = (threadIdx.x >= off) ? sh[threadIdx.x - off] : 0;
        __syncthreads();
        sh[threadIdx.x] += add;
        __syncthreads();
    }
    if (i < NODES) {
        int p = bbase[blockIdx.x] + sh[threadIdx.x] - v;  // exclusive
        rowptr[i] = p;
        cursor[i] = p;
    }
}

__global__ __launch_bounds__(256) void k_fill(const int* __restrict__ ei, int* __restrict__ cursor,
                                              int* __restrict__ csr_src) {
    int e = blockIdx.x * 256 + threadIdx.x;
    if (e < EDGES) {
        int s = ei[e];
        int d = ei[EDGES + e];
        int slot = atomicAdd(&cursor[d], 1);
        csr_src[slot] = s;
    }
}

// ---------------- casts ----------------

__global__ __launch_bounds__(256) void k_castA(const float* __restrict__ in, unsigned short* __restrict__ out, int n8) {
    int i = blockIdx.x * 256 + threadIdx.x;
    if (i >= n8) return;
    const float4* p = (const float4*)(in + (size_t)i * 8);
    float4 v0 = p[0], v1 = p[1];
    ushort4 o0, o1;
    o0.x = f2bf(v0.x); o0.y = f2bf(v0.y); o0.z = f2bf(v0.z); o0.w = f2bf(v0.w);
    o1.x = f2bf(v1.x); o1.y = f2bf(v1.y); o1.z = f2bf(v1.z); o1.w = f2bf(v1.w);
    ushort4* q = (ushort4*)(out + (size_t)i * 8);
    q[0] = o0; q[1] = o1;
}

// W (256x256 fp32, 4 of them) -> fused Wt [1024 x 256] bf16, row n = output column; + fused bias
__global__ __launch_bounds__(256) void k_castW(
    const float* __restrict__ W0, const float* __restrict__ W1,
    const float* __restrict__ W2, const float* __restrict__ W3,
    const float* __restrict__ B0, const float* __restrict__ B1,
    const float* __restrict__ B2, const float* __restrict__ B3,
    unsigned short* __restrict__ Wt, float* __restrict__ bfused)
{
    int n = blockIdx.x;           // 0..1023
    int k = threadIdx.x;          // 0..255
    int wsel = n >> 8, nn = n & 255;
    const float* W  = (wsel == 0) ? W0 : (wsel == 1) ? W1 : (wsel == 2) ? W2 : W3;
    const float* Bv = (wsel == 0) ? B0 : (wsel == 1) ? B1 : (wsel == 2) ? B2 : B3;
    Wt[(size_t)n * 256 + k] = f2bf(W[(size_t)k * 256 + nn]);
    if (k == 0) bfused[n] = Bv[nn];
}

// ---------------- bf16 MFMA GEMM, BK=64: C[M x 1024] = A[M x 256] @ Wt^T + bias, bf16 out ----------------

__global__ __launch_bounds__(256) void k_gemm_bf16(
    const unsigned short* __restrict__ A,
    const unsigned short* __restrict__ Wt,
    const float* __restrict__ bias,
    unsigned short* __restrict__ C, int M)
{
    __shared__ unsigned short As[128 * 64];
    __shared__ unsigned short Bs[128 * 64];
    int tid = threadIdx.x;
    int lane = tid & 63;
    int wave = tid >> 6;
    int wm = wave & 1, wn = wave >> 1;      // 2x2 waves -> 64x64 each
    int row0 = blockIdx.x * 128;
    int n0 = blockIdx.y * 128;

    f32x4 acc[4][4] = {};

    for (int k0 = 0; k0 < 256; k0 += 64) {
        // stage 128x64 tiles: chunk c = w*256+tid; row=c>>3, col8=(c&7)*8; dest elem = c*8
        #pragma unroll
        for (int w = 0; w < 4; w++) {
            int c = w * 256 + tid;
            int row = c >> 3;
            int cole = (c & 7) * 8;
            int ar = row0 + row; if (ar >= M) ar = M - 1;
            gload_lds16(&A[(size_t)ar * 256 + k0 + cole], &As[w * 2048 + tid * 8]);
            gload_lds16(&Wt[(size_t)(n0 + row) * 256 + k0 + cole], &Bs[w * 2048 + tid * 8]);
        }
        __syncthreads();
        int rsel = lane & 15;
        int kq = (lane >> 4) * 8;
        #pragma unroll
        for (int kh = 0; kh < 2; kh++) {
            bf16x8 af[4], bf[4];
            #pragma unroll
            for (int t = 0; t < 4; t++) {
                af[t] = *reinterpret_cast<const bf16x8*>(&As[(wm * 64 + t * 16 + rsel) * 64 + kh * 32 + kq]);
                bf[t] = *reinterpret_cast<const bf16x8*>(&Bs[(wn * 64 + t * 16 + rsel) * 64 + kh * 32 + kq]);
            }
            #pragma unroll
            for (int mt = 0; mt < 4; mt++)
                #pragma unroll
                for (int nt = 0; nt < 4; nt++)
                    acc[mt][nt] = __builtin_amdgcn_mfma_f32_16x16x32_bf16(af[mt], bf[nt], acc[mt][nt], 0, 0, 0);
        }
        __syncthreads();
    }

    // C/D mapping (verified m89/m91): col = lane&15, row = (lane>>4)*4 + reg
    int crow = (lane >> 4) * 4;
    int ccol = lane & 15;
    #pragma unroll
    for (int mt = 0; mt < 4; mt++) {
        int grow = row0 + wm * 64 + mt * 16 + crow;
        #pragma unroll
        for (int nt = 0; nt < 4; nt++) {
            int gcol = n0 + wn * 64 + nt * 16 + ccol;
            float bv = bias[gcol];
            #pragma unroll
            for (int r = 0; r < 4; r++) {
                int rr = grow + r;
                if (rr < M) C[(size_t)rr * QKVS_W + gcol] = f2bf(acc[mt][nt][r] + bv);
            }
        }
    }
}

// ---------------- attention (bf16 qkvs): one wave per node, 2 edges/iter + pairwise softmax merge ----
// qkvs row: 1024 bf16 = [q(256) | k(256) | v(256) | s(256)]
// lane l owns channels 4l..4l+3; head = l>>4; per-head reduce = xor shuffle within 16-lane group.

__global__ __launch_bounds__(256) void k_attn_bf16(const unsigned short* __restrict__ qkvs,
                                                   const int* __restrict__ rowptr,
                                                   const int* __restrict__ deg,
                                                   const int* __restrict__ csr_src,
                                                   float* __restrict__ out)
{
    int wave = threadIdx.x >> 6;
    int lane = threadIdx.x & 63;
    int node = blockIdx.x * 4 + wave;
    if (node >= NODES) return;

    const unsigned short* qrow = qkvs + (size_t)node * QKVS_W;
    float q0, q1, q2, q3;
    {
        ushort4 qv = *(const ushort4*)&qrow[lane * 4];
        q0 = bf2f(qv.x); q1 = bf2f(qv.y); q2 = bf2f(qv.z); q3 = bf2f(qv.w);
    }

    float m = -INFINITY, L = 0.f;
    float a0 = 0.f, a1 = 0.f, a2 = 0.f, a3 = 0.f;

    int start = rowptr[node];
    int cnt = deg[node];

    // process 2 edges/iter; prefetch the next pair while consuming the current one
    ushort4 kA, vA, kB, vB;
    if (cnt > 0) {
        const unsigned short* p = qkvs + (size_t)csr_src[start] * QKVS_W;
        kA = *(const ushort4*)&p[256 + lane * 4];
        vA = *(const ushort4*)&p[512 + lane * 4];
    }
    if (cnt > 1) {
        const unsigned short* p = qkvs + (size_t)csr_src[start + 1] * QKVS_W;
        kB = *(const ushort4*)&p[256 + lane * 4];
        vB = *(const ushort4*)&p[512 + lane * 4];
    }
    int e = 0;
    for (; e + 1 < cnt; e += 2) {
        ushort4 nkA, nvA, nkB, nvB;
        if (e + 2 < cnt) {
            const unsigned short* p = qkvs + (size_t)csr_src[start + e + 2] * QKVS_W;
            nkA = *(const ushort4*)&p[256 + lane * 4];
            nvA = *(const ushort4*)&p[512 + lane * 4];
        }
        if (e + 3 < cnt) {
            const unsigned short* p = qkvs + (size_t)csr_src[start + e + 3] * QKVS_W;
            nkB = *(const ushort4*)&p[256 + lane * 4];
            nvB = *(const ushort4*)&p[512 + lane * 4];
        }
        // two independent dot + shuffle-reduce chains (interleaved by the scheduler)
        float d1 = q0 * bf2f(kA.x) + q1 * bf2f(kA.y) + q2 * bf2f(kA.z) + q3 * bf2f(kA.w);
        float d2 = q0 * bf2f(kB.x) + q1 * bf2f(kB.y) + q2 * bf2f(kB.z) + q3 * bf2f(kB.w);
        d1 += __shfl_xor(d1, 1, 64);  d2 += __shfl_xor(d2, 1, 64);
        d1 += __shfl_xor(d1, 2, 64);  d2 += __shfl_xor(d2, 2, 64);
        d1 += __shfl_xor(d1, 4, 64);  d2 += __shfl_xor(d2, 4, 64);
        d1 += __shfl_xor(d1, 8, 64);  d2 += __shfl_xor(d2, 8, 64);
        float al1 = d1 * 0.125f;      // / sqrt(64)
        float al2 = d2 * 0.125f;
        // merged online-softmax update (one serial step for two edges)
        float nm = fmaxf(m, fmaxf(al1, al2));
        float sc = __expf(m - nm);    // exp(-inf)=0 on first pair
        float p1 = __expf(al1 - nm);
        float p2 = __expf(al2 - nm);
        L  = L * sc + p1 + p2;
        a0 = a0 * sc + p1 * bf2f(vA.x) + p2 * bf2f(vB.x);
        a1 = a1 * sc + p1 * bf2f(vA.y) + p2 * bf2f(vB.y);
        a2 = a2 * sc + p1 * bf2f(vA.z) + p2 * bf2f(vB.z);
        a3 = a3 * sc + p1 * bf2f(vA.w) + p2 * bf2f(vB.w);
        m = nm;
        kA = nkA; vA = nvA; kB = nkB; vB = nvB;
    }
    if (e < cnt) {   // odd tail: kA/vA hold edge cnt-1 (prefetched in the last pair iter, or at init)
        float d1 = q0 * bf2f(kA.x) + q1 * bf2f(kA.y) + q2 * bf2f(kA.z) + q3 * bf2f(kA.w);
        d1 += __shfl_xor(d1, 1, 64);
        d1 += __shfl_xor(d1, 2, 64);
        d1 += __shfl_xor(d1, 4, 64);
        d1 += __shfl_xor(d1, 8, 64);
        float al1 = d1 * 0.125f;
        float nm = fmaxf(m, al1);
        float sc = __expf(m - nm);
        float p1 = __expf(al1 - nm);
        L  = L * sc + p1;
        a0 = a0 * sc + p1 * bf2f(vA.x);
        a1 = a1 * sc + p1 * bf2f(vA.y);
        a2 = a2 * sc + p1 * bf2f(vA.z);
        a3 = a3 * sc + p1 * bf2f(vA.w);
    }

    float inv = (L > 0.f) ? 1.f / L : 0.f;
    ushort4 sv = *(const ushort4*)&qrow[768 + lane * 4];
    float4 o;
    o.x = a0 * inv + bf2f(sv.x);
    o.y = a1 * inv + bf2f(sv.y);
    o.z = a2 * inv + bf2f(sv.z);
    o.w = a3 * inv + bf2f(sv.w);
    *(float4*)&out[(size_t)node * OUT_W + lane * 4] = o;
}

// ---------------- BatchNorm ----------------

__global__ __launch_bounds__(256) void k_bnstats(const float* __restrict__ h,
                                                 float* __restrict__ sum, float* __restrict__ sumsq) {
    int col = threadIdx.x;
    int r0 = blockIdx.x * 64;
    int r1 = min(r0 + 64, NODES);
    float s = 0.f, s2 = 0.f;
    for (int r = r0; r < r1; r++) {
        float v = h[(size_t)r * OUT_W + col];
        s += v; s2 += v * v;
    }
    atomicAdd(&sum[col], s);
    atomicAdd(&sumsq[col], s2);
}

__device__ __forceinline__ float4 bn_scale4(const float* sum, const float* sumsq,
                                            const float* g, const float* be,
                                            int col, float4* shift) {
    float4 s  = *(const float4*)&sum[col];
    float4 s2 = *(const float4*)&sumsq[col];
    float4 gv = *(const float4*)&g[col];
    float4 bv = *(const float4*)&be[col];
    const float invN = 1.0f / NODES;
    float4 sc, sh;
    float mean, var;
    mean = s.x * invN; var = fmaxf(s2.x * invN - mean * mean, 0.f);
    sc.x = gv.x * rsqrtf(var + BN_EPS); sh.x = bv.x - mean * sc.x;
    mean = s.y * invN; var = fmaxf(s2.y * invN - mean * mean, 0.f);
    sc.y = gv.y * rsqrtf(var + BN_EPS); sh.y = bv.y - mean * sc.y;
    mean = s.z * invN; var = fmaxf(s2.z * invN - mean * mean, 0.f);
    sc.z = gv.z * rsqrtf(var + BN_EPS); sh.z = bv.z - mean * sc.z;
    mean = s.w * invN; var = fmaxf(s2.w * invN - mean * mean, 0.f);
    sc.w = gv.w * rsqrtf(var + BN_EPS); sh.w = bv.w - mean * sc.w;
    *shift = sh;
    return sc;
}

// layer-1 apply: fp32 in -> bf16 out (feeds GEMM2); scale/shift computed inline
__global__ __launch_bounds__(256) void k_bnapply_bf16(const float* __restrict__ h,
                                                      const float* __restrict__ sum,
                                                      const float* __restrict__ sumsq,
                                                      const float* __restrict__ g,
                                                      const float* __restrict__ be,
                                                      unsigned short* __restrict__ out) {
    int idx = blockIdx.x * 256 + threadIdx.x;
    int base = idx * 4;
    int col = base & (OUT_W - 1);
    float4 sh;
    float4 sc = bn_scale4(sum, sumsq, g, be, col, &sh);
    float4 v = *(const float4*)&h[base];
    float4 o;
    o.x = v.x * sc.x + sh.x; o.x = (o.x >= 0.f) ? o.x : 0.1f * o.x;
    o.y = v.y * sc.y + sh.y; o.y = (o.y >= 0.f) ? o.y : 0.1f * o.y;
    o.z = v.z * sc.z + sh.z; o.z = (o.z >= 0.f) ? o.z : 0.1f * o.z;
    o.w = v.w * sc.w + sh.w; o.w = (o.w >= 0.f) ? o.w : 0.1f * o.w;
    ushort4 u; u.x = f2bf(o.x); u.y = f2bf(o.y); u.z = f2bf(o.z); u.w = f2bf(o.w);
    *(ushort4*)&out[base] = u;
}

// layer-2 apply: fp32 in -> fp32 out (final output); scale/shift computed inline
__global__ __launch_bounds__(256) void k_bnapply(const float* __restrict__ h,
                                                 const float* __restrict__ sum,
                                                 const float* __restrict__ sumsq,
                                                 const float* __restrict__ g,
                                                 const float* __restrict__ be,
                                                 float* __restrict__ out) {
    int idx = blockIdx.x * 256 + threadIdx.x;
    int base = idx * 4;
    int col = base & (OUT_W - 1);
    float4 sh;
    float4 sc = bn_scale4(sum, sumsq, g, be, col, &sh);
    float4 v = *(const float4*)&h[base];
    float4 o;
    o.x = v.x * sc.x + sh.x; o.x = (o.x >= 0.f) ? o.x : 0.1f * o.x;
    o.y = v.y * sc.y + sh.y; o.y = (o.y >= 0.f) ? o.y : 0.1f * o.y;
    o.z = v.z * sc.z + sh.z; o.z = (o.z >= 0.f) ? o.z : 0.1f * o.z;
    o.w = v.w * sc.w + sh.w; o.w = (o.w >= 0.f) ? o.w : 0.1f * o.w;
    *(float4*)&out[base] = o;
}

// ---------------- launch ----------------

extern "C" void kernel_launch(void* const* d_in, const int* in_sizes, int n_in,
                              void* d_out, int out_size, void* d_ws, size_t ws_size,
                              hipStream_t stream) {
    const float* x  = (const float*)d_in[0];
    const int*   ei = (const int*)d_in[1];
    const float* w1[4] = {(const float*)d_in[2], (const float*)d_in[4], (const float*)d_in[6], (const float*)d_in[8]};
    const float* b1[4] = {(const float*)d_in[3], (const float*)d_in[5], (const float*)d_in[7], (const float*)d_in[9]};
    const float* g1  = (const float*)d_in[10];
    const float* be1 = (const float*)d_in[11];
    const float* w2[4] = {(const float*)d_in[12], (const float*)d_in[14], (const float*)d_in[16], (const float*)d_in[18]};
    const float* b2[4] = {(const float*)d_in[13], (const float*)d_in[15], (const float*)d_in[17], (const float*)d_in[19]};
    const float* g2  = (const float*)d_in[20];
    const float* be2 = (const float*)d_in[21];

    char* ws = (char*)d_ws;
    unsigned short* qkvsb  = (unsigned short*)(ws);                 // 61,440,000 (bf16 qkvs)
    float*          h1     = (float*)(ws + 61440000);               // 30,720,000
    unsigned short* abuf   = (unsigned short*)(ws + 92160000);      // 15,360,000 (bf16 GEMM input)
    unsigned short* wt1    = (unsigned short*)(ws + 107520000);     // 524,288
    unsigned short* wt2    = (unsigned short*)(ws + 108044288);     // 524,288
    float*          b1f    = (float*)(ws + 108568576);              // 4,096
    float*          b2f    = (float*)(ws + 108572672);              // 4,096
    int*            deg    = (int*)  (ws + 108576768);              // 120,000
    int*            rowptr = (int*)  (ws + 108696768);              // 120,000
    int*            cursor = (int*)  (ws + 108816768);              // 120,000
    int*            csr    = (int*)  (ws + 108936768);              // 2,400,000
    int*            bsum   = (int*)  (ws + 111336768);              // 512
    int*            bbase  = (int*)  (ws + 111337280);              // 512
    float*          sum1   = (float*)(ws + 111337792);              // 4 x 1024 contiguous
    float*          sq1    = (float*)(ws + 111338816);
    float*          sum2   = (float*)(ws + 111339840);
    float*          sq2    = (float*)(ws + 111340864);

    hipMemsetAsync(deg, 0, NODES * sizeof(int), stream);
    hipMemsetAsync(sum1, 0, 4096, stream);   // sum1/sq1/sum2/sq2 contiguous

    const int EB = (EDGES + 255) / 256;       // 2344
    const int NB = (NODES + 255) / 256;       // 118

    // casts
    k_castA<<<(NODES * 256 / 8 + 255) / 256, 256, 0, stream>>>(x, abuf, NODES * 256 / 8);
    k_castW<<<1024, 256, 0, stream>>>(w1[0], w1[1], w1[2], w1[3], b1[0], b1[1], b1[2], b1[3], wt1, b1f);
    k_castW<<<1024, 256, 0, stream>>>(w2[0], w2[1], w2[2], w2[3], b2[0], b2[1], b2[2], b2[3], wt2, b2f);

    // CSR (shared by both layers)
    k_count    <<<EB, 256, 0, stream>>>(ei, deg);
    k_blocksum <<<NB, 256, 0, stream>>>(deg, bsum);
    k_scanb    <<<1, 128, 0, stream>>>(bsum, bbase, NB);
    k_localscan<<<NB, 256, 0, stream>>>(deg, bbase, rowptr, cursor);
    k_fill     <<<EB, 256, 0, stream>>>(ei, cursor, csr);

    dim3 ggrid((NODES + 127) / 128, 8);       // 235 x 8
    const int ANB = NODES / 4;                // 7500
    const int APB = (NODES * OUT_W / 4) / 256;// 7500
    const int SNB = (NODES + 63) / 64;        // 469

    // layer 1
    k_gemm_bf16  <<<ggrid, 256, 0, stream>>>(abuf, wt1, b1f, qkvsb, NODES);
    k_attn_bf16  <<<ANB, 256, 0, stream>>>(qkvsb, rowptr, deg, csr, h1);
    k_bnstats    <<<SNB, 256, 0, stream>>>(h1, sum1, sq1);
    k_bnapply_bf16<<<APB, 256, 0, stream>>>(h1, sum1, sq1, g1, be1, abuf);

    // layer 2
    k_gemm_bf16  <<<ggrid, 256, 0, stream>>>(abuf, wt2, b2f, qkvsb, NODES);
    k_attn_bf16  <<<ANB, 256, 0, stream>>>(qkvsb, rowptr, deg, csr, h1);
    k_bnstats    <<<SNB, 256, 0, stream>>>(h1, sum2, sq2);
    k_bnapply    <<<APB, 256, 0, stream>>>(h1, sum2, sq2, g2, be2, (float*)d_out);
}

// Round 8
// 517.688 us; speedup vs baseline: 1.0523x; 1.0310x over previous
//
#include <hip/hip_runtime.h>
#include <math.h>

#define NODES 30000
#define EDGES 600000
#define QKVS_W 1024
#define OUT_W 256
#define BN_EPS 1e-5f

typedef __attribute__((ext_vector_type(8))) __bf16 bf16x8;
typedef __attribute__((ext_vector_type(4))) float f32x4;

__device__ __forceinline__ unsigned short f2bf(float f) {
    union { float f; unsigned int u; } v; v.f = f;
    unsigned int r = v.u + 0x7FFFu + ((v.u >> 16) & 1u);   // RNE
    return (unsigned short)(r >> 16);
}
__device__ __forceinline__ float bf2f(unsigned short u) {
    union { unsigned int u; float f; } v; v.u = ((unsigned int)u) << 16;
    return v.f;
}

typedef const __attribute__((address_space(1))) void* gas_p;
typedef __attribute__((address_space(3))) void* las_p;
__device__ __forceinline__ void gload_lds16(const void* g, void* l) {
    __builtin_amdgcn_global_load_lds((gas_p)g, (las_p)l, 16, 0, 0);
}

// ---------------- CSR build ----------------

__global__ __launch_bounds__(256) void k_count(const int* __restrict__ ei, int* __restrict__ deg) {
    int e = blockIdx.x * 256 + threadIdx.x;
    if (e < EDGES) atomicAdd(&deg[ei[EDGES + e]], 1);   // dst row
}

__global__ __launch_bounds__(256) void k_blocksum(const int* __restrict__ deg, int* __restrict__ bsum) {
    __shared__ int sh[256];
    int i = blockIdx.x * 256 + threadIdx.x;
    sh[threadIdx.x] = (i < NODES) ? deg[i] : 0;
    __syncthreads();
    for (int off = 128; off > 0; off >>= 1) {
        if (threadIdx.x < off) sh[threadIdx.x] += sh[threadIdx.x + off];
        __syncthreads();
    }
    if (threadIdx.x == 0) bsum[blockIdx.x] = sh[0];
}

// parallel exclusive scan over <=128 block sums (LDS Hillis-Steele)
__global__ __launch_bounds__(128) void k_scanb(const int* __restrict__ bsum, int* __restrict__ bbase, int nb) {
    __shared__ int sh[128];
    int t = threadIdx.x;
    int v = (t < nb) ? bsum[t] : 0;
    sh[t] = v;
    __syncthreads();
    for (int off = 1; off < 128; off <<= 1) {
        int add = (t >= off) ? sh[t - off] : 0;
        __syncthreads();
        sh[t] += add;
        __syncthreads();
    }
    if (t < nb) bbase[t] = sh[t] - v;   // exclusive
}

__global__ __launch_bounds__(256) void k_localscan(const int* __restrict__ deg, const int* __restrict__ bbase,
                                                   int* __restrict__ rowptr, int* __restrict__ cursor) {
    __shared__ int sh[256];
    int i = blockIdx.x * 256 + threadIdx.x;
    int v = (i < NODES) ? deg[i] : 0;
    sh[threadIdx.x] = v;
    __syncthreads();
    for (int off = 1; off < 256; off <<= 1) {
        int add = (threadIdx.x >= off) ? sh[threadIdx.x - off] : 0;
        __syncthreads();
        sh[threadIdx.x] += add;
        __syncthreads();
    }
    if (i < NODES) {
        int p = bbase[blockIdx.x] + sh[threadIdx.x] - v;  // exclusive
        rowptr[i] = p;
        cursor[i] = p;
    }
}

__global__ __launch_bounds__(256) void k_fill(const int* __restrict__ ei, int* __restrict__ cursor,
                                              int* __restrict__ csr_src) {
    int e = blockIdx.x * 256 + threadIdx.x;
    if (e < EDGES) {
        int s = ei[e];
        int d = ei[EDGES + e];
        int slot = atomicAdd(&cursor[d], 1);
        csr_src[slot] = s;
    }
}

// ---------------- casts ----------------

__global__ __launch_bounds__(256) void k_castA(const float* __restrict__ in, unsigned short* __restrict__ out, int n8) {
    int i = blockIdx.x * 256 + threadIdx.x;
    if (i >= n8) return;
    const float4* p = (const float4*)(in + (size_t)i * 8);
    float4 v0 = p[0], v1 = p[1];
    ushort4 o0, o1;
    o0.x = f2bf(v0.x); o0.y = f2bf(v0.y); o0.z = f2bf(v0.z); o0.w = f2bf(v0.w);
    o1.x = f2bf(v1.x); o1.y = f2bf(v1.y); o1.z = f2bf(v1.z); o1.w = f2bf(v1.w);
    ushort4* q = (ushort4*)(out + (size_t)i * 8);
    q[0] = o0; q[1] = o1;
}

// both layers' W (256x256 fp32, 4 each) -> fused Wt [1024 x 256] bf16 (row n = output col) + bias
__global__ __launch_bounds__(256) void k_castW2(
    const float* __restrict__ Wa0, const float* __restrict__ Wa1,
    const float* __restrict__ Wa2, const float* __restrict__ Wa3,
    const float* __restrict__ Ba0, const float* __restrict__ Ba1,
    const float* __restrict__ Ba2, const float* __restrict__ Ba3,
    const float* __restrict__ Wb0, const float* __restrict__ Wb1,
    const float* __restrict__ Wb2, const float* __restrict__ Wb3,
    const float* __restrict__ Bb0, const float* __restrict__ Bb1,
    const float* __restrict__ Bb2, const float* __restrict__ Bb3,
    unsigned short* __restrict__ Wt1, float* __restrict__ bf1,
    unsigned short* __restrict__ Wt2, float* __restrict__ bf2)
{
    int nn0 = blockIdx.x;         // 0..2047
    int layer = nn0 >> 10;
    int n = nn0 & 1023;
    int k = threadIdx.x;          // 0..255
    int wsel = n >> 8, nc = n & 255;
    const float* W; const float* Bv;
    if (layer == 0) {
        W  = (wsel == 0) ? Wa0 : (wsel == 1) ? Wa1 : (wsel == 2) ? Wa2 : Wa3;
        Bv = (wsel == 0) ? Ba0 : (wsel == 1) ? Ba1 : (wsel == 2) ? Ba2 : Ba3;
    } else {
        W  = (wsel == 0) ? Wb0 : (wsel == 1) ? Wb1 : (wsel == 2) ? Wb2 : Wb3;
        Bv = (wsel == 0) ? Bb0 : (wsel == 1) ? Bb1 : (wsel == 2) ? Bb2 : Bb3;
    }
    unsigned short* Wt = (layer == 0) ? Wt1 : Wt2;
    float* bfused = (layer == 0) ? bf1 : bf2;
    Wt[(size_t)n * 256 + k] = f2bf(W[(size_t)k * 256 + nc]);
    if (k == 0) bfused[n] = Bv[nc];
}

// ---------------- bf16 MFMA GEMM, BK=64, LDS-staged coalesced epilogue ----------------

#define CS 136   // padded LDS stride (ushorts) for the 128x128 C tile

__global__ __launch_bounds__(256) void k_gemm_bf16(
    const unsigned short* __restrict__ A,
    const unsigned short* __restrict__ Wt,
    const float* __restrict__ bias,
    unsigned short* __restrict__ C, int M)
{
    __shared__ unsigned short sbuf[128 * CS];   // 34,816 B; unions staging (32KB) and epilogue
    unsigned short* As = sbuf;                  // 128*64
    unsigned short* Bs = sbuf + 8192;           // 128*64
    int tid = threadIdx.x;
    int lane = tid & 63;
    int wave = tid >> 6;
    int wm = wave & 1, wn = wave >> 1;      // 2x2 waves -> 64x64 each
    int row0 = blockIdx.x * 128;
    int n0 = blockIdx.y * 128;

    f32x4 acc[4][4] = {};

    for (int k0 = 0; k0 < 256; k0 += 64) {
        // stage 128x64 tiles: chunk c = w*256+tid; row=c>>3, col8=(c&7)*8; dest elem = c*8
        #pragma unroll
        for (int w = 0; w < 4; w++) {
            int c = w * 256 + tid;
            int row = c >> 3;
            int cole = (c & 7) * 8;
            int ar = row0 + row; if (ar >= M) ar = M - 1;
            gload_lds16(&A[(size_t)ar * 256 + k0 + cole], &As[w * 2048 + tid * 8]);
            gload_lds16(&Wt[(size_t)(n0 + row) * 256 + k0 + cole], &Bs[w * 2048 + tid * 8]);
        }
        __syncthreads();
        int rsel = lane & 15;
        int kq = (lane >> 4) * 8;
        #pragma unroll
        for (int kh = 0; kh < 2; kh++) {
            bf16x8 af[4], bf[4];
            #pragma unroll
            for (int t = 0; t < 4; t++) {
                af[t] = *reinterpret_cast<const bf16x8*>(&As[(wm * 64 + t * 16 + rsel) * 64 + kh * 32 + kq]);
                bf[t] = *reinterpret_cast<const bf16x8*>(&Bs[(wn * 64 + t * 16 + rsel) * 64 + kh * 32 + kq]);
            }
            #pragma unroll
            for (int mt = 0; mt < 4; mt++)
                #pragma unroll
                for (int nt = 0; nt < 4; nt++)
                    acc[mt][nt] = __builtin_amdgcn_mfma_f32_16x16x32_bf16(af[mt], bf[nt], acc[mt][nt], 0, 0, 0);
        }
        __syncthreads();
    }

    // epilogue: C/D mapping (verified m89/m91): col = lane&15, row = (lane>>4)*4 + reg
    // stage bf16 (+bias) tile into padded LDS, then coalesced 16B stores.
    int crow = (lane >> 4) * 4;
    int ccol = lane & 15;
    #pragma unroll
    for (int mt = 0; mt < 4; mt++) {
        int lrow = wm * 64 + mt * 16 + crow;
        #pragma unroll
        for (int nt = 0; nt < 4; nt++) {
            int lcol = wn * 64 + nt * 16 + ccol;
            float bv = bias[n0 + lcol];
            #pragma unroll
            for (int r = 0; r < 4; r++)
                sbuf[(lrow + r) * CS + lcol] = f2bf(acc[mt][nt][r] + bv);
        }
    }
    __syncthreads();
    // 16 lanes cover one row's 128 cols (16 x 16B); 8 row-groups per thread
    int chunk = tid & 15;
    int rbase = tid >> 4;
    #pragma unroll
    for (int g = 0; g < 8; g++) {
        int row_l = g * 16 + rbase;
        int gr = row0 + row_l;
        if (gr < M) {
            uint4 val = *(const uint4*)&sbuf[row_l * CS + chunk * 8];
            *(uint4*)&C[(size_t)gr * QKVS_W + n0 + chunk * 8] = val;
        }
    }
}

// ---------------- attention (bf16 qkvs): one wave per node, 2 edges/iter + pairwise softmax merge ----
// qkvs row: 1024 bf16 = [q(256) | k(256) | v(256) | s(256)]
// lane l owns channels 4l..4l+3; head = l>>4; per-head reduce = xor shuffle within 16-lane group.

__global__ __launch_bounds__(256) void k_attn_bf16(const unsigned short* __restrict__ qkvs,
                                                   const int* __restrict__ rowptr,
                                                   const int* __restrict__ deg,
                                                   const int* __restrict__ csr_src,
                                                   float* __restrict__ out)
{
    int wave = threadIdx.x >> 6;
    int lane = threadIdx.x & 63;
    int node = blockIdx.x * 4 + wave;
    if (node >= NODES) return;

    const unsigned short* qrow = qkvs + (size_t)node * QKVS_W;
    float q0, q1, q2, q3;
    {
        ushort4 qv = *(const ushort4*)&qrow[lane * 4];
        q0 = bf2f(qv.x); q1 = bf2f(qv.y); q2 = bf2f(qv.z); q3 = bf2f(qv.w);
    }

    float m = -INFINITY, L = 0.f;
    float a0 = 0.f, a1 = 0.f, a2 = 0.f, a3 = 0.f;

    int start = rowptr[node];
    int cnt = deg[node];

    // process 2 edges/iter; prefetch the next pair while consuming the current one
    ushort4 kA, vA, kB, vB;
    if (cnt > 0) {
        const unsigned short* p = qkvs + (size_t)csr_src[start] * QKVS_W;
        kA = *(const ushort4*)&p[256 + lane * 4];
        vA = *(const ushort4*)&p[512 + lane * 4];
    }
    if (cnt > 1) {
        const unsigned short* p = qkvs + (size_t)csr_src[start + 1] * QKVS_W;
        kB = *(const ushort4*)&p[256 + lane * 4];
        vB = *(const ushort4*)&p[512 + lane * 4];
    }
    int e = 0;
    for (; e + 1 < cnt; e += 2) {
        ushort4 nkA, nvA, nkB, nvB;
        if (e + 2 < cnt) {
            const unsigned short* p = qkvs + (size_t)csr_src[start + e + 2] * QKVS_W;
            nkA = *(const ushort4*)&p[256 + lane * 4];
            nvA = *(const ushort4*)&p[512 + lane * 4];
        }
        if (e + 3 < cnt) {
            const unsigned short* p = qkvs + (size_t)csr_src[start + e + 3] * QKVS_W;
            nkB = *(const ushort4*)&p[256 + lane * 4];
            nvB = *(const ushort4*)&p[512 + lane * 4];
        }
        float d1 = q0 * bf2f(kA.x) + q1 * bf2f(kA.y) + q2 * bf2f(kA.z) + q3 * bf2f(kA.w);
        float d2 = q0 * bf2f(kB.x) + q1 * bf2f(kB.y) + q2 * bf2f(kB.z) + q3 * bf2f(kB.w);
        d1 += __shfl_xor(d1, 1, 64);  d2 += __shfl_xor(d2, 1, 64);
        d1 += __shfl_xor(d1, 2, 64);  d2 += __shfl_xor(d2, 2, 64);
        d1 += __shfl_xor(d1, 4, 64);  d2 += __shfl_xor(d2, 4, 64);
        d1 += __shfl_xor(d1, 8, 64);  d2 += __shfl_xor(d2, 8, 64);
        float al1 = d1 * 0.125f;      // / sqrt(64)
        float al2 = d2 * 0.125f;
        float nm = fmaxf(m, fmaxf(al1, al2));
        float sc = __expf(m - nm);    // exp(-inf)=0 on first pair
        float p1 = __expf(al1 - nm);
        float p2 = __expf(al2 - nm);
        L  = L * sc + p1 + p2;
        a0 = a0 * sc + p1 * bf2f(vA.x) + p2 * bf2f(vB.x);
        a1 = a1 * sc + p1 * bf2f(vA.y) + p2 * bf2f(vB.y);
        a2 = a2 * sc + p1 * bf2f(vA.z) + p2 * bf2f(vB.z);
        a3 = a3 * sc + p1 * bf2f(vA.w) + p2 * bf2f(vB.w);
        m = nm;
        kA = nkA; vA = nvA; kB = nkB; vB = nvB;
    }
    if (e < cnt) {   // odd tail: kA/vA hold edge cnt-1
        float d1 = q0 * bf2f(kA.x) + q1 * bf2f(kA.y) + q2 * bf2f(kA.z) + q3 * bf2f(kA.w);
        d1 += __shfl_xor(d1, 1, 64);
        d1 += __shfl_xor(d1, 2, 64);
        d1 += __shfl_xor(d1, 4, 64);
        d1 += __shfl_xor(d1, 8, 64);
        float al1 = d1 * 0.125f;
        float nm = fmaxf(m, al1);
        float sc = __expf(m - nm);
        float p1 = __expf(al1 - nm);
        L  = L * sc + p1;
        a0 = a0 * sc + p1 * bf2f(vA.x);
        a1 = a1 * sc + p1 * bf2f(vA.y);
        a2 = a2 * sc + p1 * bf2f(vA.z);
        a3 = a3 * sc + p1 * bf2f(vA.w);
    }

    float inv = (L > 0.f) ? 1.f / L : 0.f;
    ushort4 sv = *(const ushort4*)&qrow[768 + lane * 4];
    float4 o;
    o.x = a0 * inv + bf2f(sv.x);
    o.y = a1 * inv + bf2f(sv.y);
    o.z = a2 * inv + bf2f(sv.z);
    o.w = a3 * inv + bf2f(sv.w);
    *(float4*)&out[(size_t)node * OUT_W + lane * 4] = o;
}

// ---------------- BatchNorm ----------------

__global__ __launch_bounds__(256) void k_bnstats(const float* __restrict__ h,
                                                 float* __restrict__ sum, float* __restrict__ sumsq) {
    int col = threadIdx.x;
    int r0 = blockIdx.x * 64;
    int r1 = min(r0 + 64, NODES);
    float s = 0.f, s2 = 0.f;
    for (int r = r0; r < r1; r++) {
        float v = h[(size_t)r * OUT_W + col];
        s += v; s2 += v * v;
    }
    atomicAdd(&sum[col], s);
    atomicAdd(&sumsq[col], s2);
}

__device__ __forceinline__ float4 bn_scale4(const float* sum, const float* sumsq,
                                            const float* g, const float* be,
                                            int col, float4* shift) {
    float4 s  = *(const float4*)&sum[col];
    float4 s2 = *(const float4*)&sumsq[col];
    float4 gv = *(const float4*)&g[col];
    float4 bv = *(const float4*)&be[col];
    const float invN = 1.0f / NODES;
    float4 sc, sh;
    float mean, var;
    mean = s.x * invN; var = fmaxf(s2.x * invN - mean * mean, 0.f);
    sc.x = gv.x * rsqrtf(var + BN_EPS); sh.x = bv.x - mean * sc.x;
    mean = s.y * invN; var = fmaxf(s2.y * invN - mean * mean, 0.f);
    sc.y = gv.y * rsqrtf(var + BN_EPS); sh.y = bv.y - mean * sc.y;
    mean = s.z * invN; var = fmaxf(s2.z * invN - mean * mean, 0.f);
    sc.z = gv.z * rsqrtf(var + BN_EPS); sh.z = bv.z - mean * sc.z;
    mean = s.w * invN; var = fmaxf(s2.w * invN - mean * mean, 0.f);
    sc.w = gv.w * rsqrtf(var + BN_EPS); sh.w = bv.w - mean * sc.w;
    *shift = sh;
    return sc;
}

// layer-1 apply: fp32 in -> bf16 out (feeds GEMM2); scale/shift computed inline
__global__ __launch_bounds__(256) void k_bnapply_bf16(const float* __restrict__ h,
                                                      const float* __restrict__ sum,
                                                      const float* __restrict__ sumsq,
                                                      const float* __restrict__ g,
                                                      const float* __restrict__ be,
                                                      unsigned short* __restrict__ out) {
    int idx = blockIdx.x * 256 + threadIdx.x;
    int base = idx * 4;
    int col = base & (OUT_W - 1);
    float4 sh;
    float4 sc = bn_scale4(sum, sumsq, g, be, col, &sh);
    float4 v = *(const float4*)&h[base];
    float4 o;
    o.x = v.x * sc.x + sh.x; o.x = (o.x >= 0.f) ? o.x : 0.1f * o.x;
    o.y = v.y * sc.y + sh.y; o.y = (o.y >= 0.f) ? o.y : 0.1f * o.y;
    o.z = v.z * sc.z + sh.z; o.z = (o.z >= 0.f) ? o.z : 0.1f * o.z;
    o.w = v.w * sc.w + sh.w; o.w = (o.w >= 0.f) ? o.w : 0.1f * o.w;
    ushort4 u; u.x = f2bf(o.x); u.y = f2bf(o.y); u.z = f2bf(o.z); u.w = f2bf(o.w);
    *(ushort4*)&out[base] = u;
}

// layer-2 apply: fp32 in -> fp32 out (final output); scale/shift computed inline
__global__ __launch_bounds__(256) void k_bnapply(const float* __restrict__ h,
                                                 const float* __restrict__ sum,
                                                 const float* __restrict__ sumsq,
                                                 const float* __restrict__ g,
                                                 const float* __restrict__ be,
                                                 float* __restrict__ out) {
    int idx = blockIdx.x * 256 + threadIdx.x;
    int base = idx * 4;
    int col = base & (OUT_W - 1);
    float4 sh;
    float4 sc = bn_scale4(sum, sumsq, g, be, col, &sh);
    float4 v = *(const float4*)&h[base];
    float4 o;
    o.x = v.x * sc.x + sh.x; o.x = (o.x >= 0.f) ? o.x : 0.1f * o.x;
    o.y = v.y * sc.y + sh.y; o.y = (o.y >= 0.f) ? o.y : 0.1f * o.y;
    o.z = v.z * sc.z + sh.z; o.z = (o.z >= 0.f) ? o.z : 0.1f * o.z;
    o.w = v.w * sc.w + sh.w; o.w = (o.w >= 0.f) ? o.w : 0.1f * o.w;
    *(float4*)&out[base] = o;
}

// ---------------- launch ----------------

extern "C" void kernel_launch(void* const* d_in, const int* in_sizes, int n_in,
                              void* d_out, int out_size, void* d_ws, size_t ws_size,
                              hipStream_t stream) {
    const float* x  = (const float*)d_in[0];
    const int*   ei = (const int*)d_in[1];
    const float* w1[4] = {(const float*)d_in[2], (const float*)d_in[4], (const float*)d_in[6], (const float*)d_in[8]};
    const float* b1[4] = {(const float*)d_in[3], (const float*)d_in[5], (const float*)d_in[7], (const float*)d_in[9]};
    const float* g1  = (const float*)d_in[10];
    const float* be1 = (const float*)d_in[11];
    const float* w2[4] = {(const float*)d_in[12], (const float*)d_in[14], (const float*)d_in[16], (const float*)d_in[18]};
    const float* b2[4] = {(const float*)d_in[13], (const float*)d_in[15], (const float*)d_in[17], (const float*)d_in[19]};
    const float* g2  = (const float*)d_in[20];
    const float* be2 = (const float*)d_in[21];

    char* ws = (char*)d_ws;
    unsigned short* qkvsb  = (unsigned short*)(ws);                 // 61,440,000 (bf16 qkvs)
    float*          h1     = (float*)(ws + 61440000);               // 30,720,000
    unsigned short* abuf   = (unsigned short*)(ws + 92160000);      // 15,360,000 (bf16 GEMM input)
    unsigned short* wt1    = (unsigned short*)(ws + 107520000);     // 524,288
    unsigned short* wt2    = (unsigned short*)(ws + 108044288);     // 524,288
    float*          b1f    = (float*)(ws + 108568576);              // 4,096
    float*          b2f    = (float*)(ws + 108572672);              // 4,096
    int*            deg    = (int*)  (ws + 108576768);              // 120,000
    int*            rowptr = (int*)  (ws + 108696768);              // 120,000
    int*            cursor = (int*)  (ws + 108816768);              // 120,000
    int*            csr    = (int*)  (ws + 108936768);              // 2,400,000
    int*            bsum   = (int*)  (ws + 111336768);              // 512
    int*            bbase  = (int*)  (ws + 111337280);              // 512
    float*          sum1   = (float*)(ws + 111337792);              // 4 x 1024 contiguous
    float*          sq1    = (float*)(ws + 111338816);
    float*          sum2   = (float*)(ws + 111339840);
    float*          sq2    = (float*)(ws + 111340864);

    hipMemsetAsync(deg, 0, NODES * sizeof(int), stream);
    hipMemsetAsync(sum1, 0, 4096, stream);   // sum1/sq1/sum2/sq2 contiguous

    const int EB = (EDGES + 255) / 256;       // 2344
    const int NB = (NODES + 255) / 256;       // 118

    // casts
    k_castA<<<(NODES * 256 / 8 + 255) / 256, 256, 0, stream>>>(x, abuf, NODES * 256 / 8);
    k_castW2<<<2048, 256, 0, stream>>>(w1[0], w1[1], w1[2], w1[3], b1[0], b1[1], b1[2], b1[3],
                                       w2[0], w2[1], w2[2], w2[3], b2[0], b2[1], b2[2], b2[3],
                                       wt1, b1f, wt2, b2f);

    // CSR (shared by both layers)
    k_count    <<<EB, 256, 0, stream>>>(ei, deg);
    k_blocksum <<<NB, 256, 0, stream>>>(deg, bsum);
    k_scanb    <<<1, 128, 0, stream>>>(bsum, bbase, NB);
    k_localscan<<<NB, 256, 0, stream>>>(deg, bbase, rowptr, cursor);
    k_fill     <<<EB, 256, 0, stream>>>(ei, cursor, csr);

    dim3 ggrid((NODES + 127) / 128, 8);       // 235 x 8
    const int ANB = NODES / 4;                // 7500
    const int APB = (NODES * OUT_W / 4) / 256;// 7500
    const int SNB = (NODES + 63) / 64;        // 469

    // layer 1
    k_gemm_bf16  <<<ggrid, 256, 0, stream>>>(abuf, wt1, b1f, qkvsb, NODES);
    k_attn_bf16  <<<ANB, 256, 0, stream>>>(qkvsb, rowptr, deg, csr, h1);
    k_bnstats    <<<SNB, 256, 0, stream>>>(h1, sum1, sq1);
    k_bnapply_bf16<<<APB, 256, 0, stream>>>(h1, sum1, sq1, g1, be1, abuf);

    // layer 2
    k_gemm_bf16  <<<ggrid, 256, 0, stream>>>(abuf, wt2, b2f, qkvsb, NODES);
    k_attn_bf16  <<<ANB, 256, 0, stream>>>(qkvsb, rowptr, deg, csr, h1);
    k_bnstats    <<<SNB, 256, 0, stream>>>(h1, sum2, sq2);
    k_bnapply    <<<APB, 256, 0, stream>>>(h1, sum2, sq2, g2, be2, (float*)d_out);
}